// Round 13
// baseline (74.757 us; speedup 1.0000x reference)
//
#include <hip/hip_runtime.h>
#include <cstdint>

typedef short bf16x8 __attribute__((ext_vector_type(8)));
typedef float f32x4 __attribute__((ext_vector_type(4)));

#define NO 8
#define NT 4
#define ND 256
#define NH1 64
#define NH2 32
#define BM 128
#define BNEPS 1e-5f

#define GLD(srcp, dstp) __builtin_amdgcn_global_load_lds( \
    (const __attribute__((address_space(1))) void*)(srcp), \
    (__attribute__((address_space(3))) void*)(dstp), 16, 0, 0)

__device__ __forceinline__ unsigned bfpack2(float a, float b) {
    unsigned ua = __float_as_uint(a), ub = __float_as_uint(b);
    ua = (ua + 0x7FFFu + ((ua >> 16) & 1u)) >> 16;
    ub = (ub + 0x7FFFu + ((ub >> 16) & 1u)) >> 16;
    return ua | (ub << 16);
}

__device__ __forceinline__ unsigned cvtpk(float lo, float hi) {
    unsigned r;
    asm("v_cvt_pk_bf16_f32 %0, %1, %2" : "=v"(r) : "v"(lo), "v"(hi));
    return r;
}

// ws layout (bytes):
//   [0,64): int cnt[4] @0, cursor[4] @16  (zeroed by memset)
//   rperm[B+512]: padded slot -> row id (-1 holes; memset 0xFF)
//   W1T (1 MB), W2T (128 KB), P1 (24 KB), P2 (12 KB)

__global__ void k_hist_prep(const int* __restrict__ trt, int* __restrict__ ws, int B,
                            const float* __restrict__ W1, const float* __restrict__ W2,
                            const float* __restrict__ b1, const float* __restrict__ g1,
                            const float* __restrict__ be1, const float* __restrict__ m1,
                            const float* __restrict__ v1,
                            const float* __restrict__ b2, const float* __restrict__ g2,
                            const float* __restrict__ be2, const float* __restrict__ m2,
                            const float* __restrict__ v2, const float* __restrict__ W3,
                            unsigned* __restrict__ W1T4, unsigned* __restrict__ W2T4,
                            float* __restrict__ P1, float* __restrict__ P2) {
    const int bid = blockIdx.x, tid = threadIdx.x;
    if (bid < 256) {                                      // ---- histogram ----
        __shared__ int loc[NT];
        if (tid < NT) loc[tid] = 0;
        __syncthreads();
        const int i = bid * 256 + tid;
        if (i < B) atomicAdd(&loc[trt[i] & 3], 1);
        __syncthreads();
        if (tid < NT) atomicAdd(&ws[tid], loc[tid]);
    } else if (bid < 512) {                               // ---- W1T frags ----
        const int gi = (bid - 256) * 256 + tid;           // 65536
        const int lane = gi & 63, nt = (gi >> 6) & 31, c = (gi >> 11) & 7, t = gi >> 14;
        const int n16 = lane & 15, kg = lane >> 4;
        const int n = nt * 16 + n16, o = n >> 6, h = n & 63;
        const int k0 = c * 32 + kg * 8;
        const float* src = W1 + ((size_t)(o * NT + t) * ND + k0) * NH1 + h;
        float v[8];
#pragma unroll
        for (int j = 0; j < 8; ++j) v[j] = src[(size_t)j * NH1];
        uint4 q;
        q.x = bfpack2(v[0], v[1]); q.y = bfpack2(v[2], v[3]);
        q.z = bfpack2(v[4], v[5]); q.w = bfpack2(v[6], v[7]);
        ((uint4*)W1T4)[gi] = q;
    } else if (bid < 544) {                               // ---- W2T frags ----
        const int gi = (bid - 512) * 256 + tid;           // 8192
        const int m16 = gi & 15, kg = (gi >> 4) & 3, ks = (gi >> 6) & 1,
                  kt = (gi >> 7) & 1, o = (gi >> 8) & 7, t = gi >> 11;
        const int k2 = kt * 16 + m16, hb = ks * 32 + kg * 8;
        const float* src = W2 + ((size_t)(o * NT + t) * NH1 + hb) * NH2 + k2;
        float v[8];
#pragma unroll
        for (int j = 0; j < 8; ++j) v[j] = src[(size_t)j * NH2];
        uint4 q;
        q.x = bfpack2(v[0], v[1]); q.y = bfpack2(v[2], v[3]);
        q.z = bfpack2(v[4], v[5]); q.w = bfpack2(v[6], v[7]);
        ((uint4*)W2T4)[gi] = q;
    } else if (bid < 552) {                               // ---- P1: BN1 fold ----
        const int gi = (bid - 544) * 256 + tid;           // 2048 = 4t x 512n
        const int t = gi >> 9, n = gi & 511;
        const int o = n >> 6, h = n & 63;
        const int idx = (o * NT + t) * NH1 + h;
        const float sc = g1[idx] * rsqrtf(v1[idx] + BNEPS);
        P1[gi] = sc;
        P1[2048 + gi] = be1[idx] - m1[idx] * sc;
        P1[4096 + gi] = b1[idx];
    } else {                                              // ---- P2: BN2+W3 fold ----
        const int gi = (bid - 552) * 256 + tid;           // 1024 = 4t x 256(o,k2)
        const int t = gi >> 8, q = gi & 255;
        const int o = q >> 5, k2 = q & 31;
        const int idx = (o * NT + t) * NH2 + k2;
        const float s = g2[idx] * rsqrtf(v2[idx] + BNEPS);
        const float w3 = W3[idx];
        P2[gi] = s * w3;
        P2[1024 + gi] = (be2[idx] - m2[idx] * s) * w3;
        P2[2048 + gi] = b2[idx];
    }
}

__global__ void k_scatter(const int* __restrict__ trt, int* __restrict__ ws,
                          int* __restrict__ rperm, int B) {
    __shared__ int loc[NT], gb[NT];
    const int tid = threadIdx.x;
    if (tid < NT) loc[tid] = 0;
    __syncthreads();
    const int i = blockIdx.x * blockDim.x + tid;
    int tt = 0, pos = 0;
    if (i < B) { tt = trt[i] & 3; pos = atomicAdd(&loc[tt], 1); }
    __syncthreads();
    if (tid < NT) {
        const int c0 = ws[0], c1 = ws[1], c2 = ws[2];
        const int q0 = (c0 + 127) & ~127, q1 = (c1 + 127) & ~127, q2 = (c2 + 127) & ~127;
        const int eb = tid == 0 ? 0 : tid == 1 ? q0 : tid == 2 ? q0 + q1 : q0 + q1 + q2;
        gb[tid] = eb + atomicAdd(&ws[4 + tid], loc[tid]);
    }
    __syncthreads();
    if (i < B) rperm[gb[tt] + pos] = i;
}

// ---------------- fused 3-layer expert MLP: 128-row x 512-col blocks, 8 waves ----------------
// wave w: ngrp=w&3 (col block of 128), rgrp=w>>2 (row block of 64). acc[8][4] per wave.
// LDS: XB dbuf [0,32K) 2 x (128 r x 128 B fp32, K-major, XOR-source-swizzled);
//      WB dbuf [32K,96K) 2 x 32 KB. After K-loop all 128 KB becomes Hr[128][1024B].
__global__ __launch_bounds__(512, 2) void k_main(
    const float* __restrict__ X, const int* __restrict__ ws, const int* __restrict__ rperm,
    const char* __restrict__ W1T, const char* __restrict__ W2T,
    const float* __restrict__ P1, const float* __restrict__ P2,
    const float* __restrict__ pb3, float* __restrict__ out)
{
    const int c0 = ws[0], c1 = ws[1], c2 = ws[2], c3 = ws[3];
    const int q0 = (c0 + 127) & ~127, q1 = (c1 + 127) & ~127, q2 = (c2 + 127) & ~127;
    const int e0 = q0, e1 = q0 + q1, e2 = e1 + q2, e3 = e2 + ((c3 + 127) & ~127);
    const int m0 = blockIdx.x * BM;
    if (m0 >= e3) return;
    const int t = (m0 >= e0) + (m0 >= e1) + (m0 >= e2);

    const int tid = threadIdx.x;
    const int w = tid >> 6;          // 0..7
    const int l = tid & 63;
    const int ngrp = w & 3, rgrp = w >> 2;

    __shared__ __align__(16) char LDS[131072];
    char* const XB = LDS;            // 2 x 16384
    char* const WB = LDS + 32768;    // 2 x 32768

    const int rid_lo = rperm[m0 + l];
    const int rid_hi = rperm[m0 + 64 + l];

    const char* Xb = (const char*)X;
    const char* W1Tt = W1T + (size_t)t * 262144;
    const int ln4 = (l >> 4) * 4;

    // per-wave X-gather geometry: inst j covers 8 rows; row = w*16 + j*8 + (l>>3)
    const int xrow_in = (w & 3) * 16 + (l >> 3);             // + j*8, +64 if w>=4
    const unsigned xsoff = (unsigned)((l & 7) * 16) ^ (unsigned)(((l >> 3) & 7) << 4);

    // ---- stage chunk 0 (X + W), fire-and-forget ----
#pragma unroll
    for (int j = 0; j < 2; ++j) {
        const int rloc = (w >> 2) ? 64 + xrow_in + j * 8 - 64 + 64 : xrow_in + j * 8;  // resolved below
    }
    // (explicit, avoiding the dummy loop above)
    {
#pragma unroll
        for (int j = 0; j < 2; ++j) {
            const int row = (w >> 2) * 64 + (w & 3) * 16 + j * 8 + (l >> 3);
            const int rr = (w >> 2) ? __shfl(rid_hi, (w & 3) * 16 + j * 8 + (l >> 3))
                                    : __shfl(rid_lo, (w & 3) * 16 + j * 8 + (l >> 3));
            const size_t rowb = (size_t)(rr < 0 ? 0 : rr) * 1024;
            GLD(Xb + rowb + 0 * 128 + xsoff, XB + row * 128 + (l & 7) * 16);
        }
#pragma unroll
        for (int u = 0; u < 4; ++u) {
            const int sl = w * 4096 + u * 1024 + l * 16;
            GLD(W1Tt + sl, WB + sl);
        }
    }

    // acc init = b1 (bias folded into accumulator)
    f32x4 acc[8][4];
#pragma unroll
    for (int nt = 0; nt < 8; ++nt) {
        const int n0 = (ngrp * 8 + nt) * 16 + ln4;
        const float4 bbv = *(const float4*)(P1 + 4096 + t * 512 + n0);
        acc[nt][0] = (f32x4){bbv.x, bbv.y, bbv.z, bbv.w};
        acc[nt][1] = acc[nt][0];
        acc[nt][2] = acc[nt][0];
        acc[nt][3] = acc[nt][0];
    }

    __syncthreads();     // chunk 0 visible

    // ---- K-loop: issue (c+1) GLDs, compute (c), barrier ----
#pragma unroll
    for (int c = 0; c < 8; ++c) {
        const int cur = c & 1, nxt = cur ^ 1;
        if (c < 7) {
#pragma unroll
            for (int j = 0; j < 2; ++j) {
                const int row = (w >> 2) * 64 + (w & 3) * 16 + j * 8 + (l >> 3);
                const int rr = (w >> 2) ? __shfl(rid_hi, (w & 3) * 16 + j * 8 + (l >> 3))
                                        : __shfl(rid_lo, (w & 3) * 16 + j * 8 + (l >> 3));
                const size_t rowb = (size_t)(rr < 0 ? 0 : rr) * 1024;
                GLD(Xb + rowb + (c + 1) * 128 + xsoff, XB + nxt * 16384 + row * 128 + (l & 7) * 16);
            }
#pragma unroll
            for (int u = 0; u < 4; ++u) {
                const int sl = w * 4096 + u * 1024 + l * 16;
                GLD(W1Tt + (c + 1) * 32768 + sl, WB + nxt * 32768 + sl);
            }
        }
        // compute chunk c
        bf16x8 aA[8];
#pragma unroll
        for (int nt = 0; nt < 8; ++nt)
            aA[nt] = *(const bf16x8*)(WB + cur * 32768 + (ngrp * 8 + nt) * 1024 + l * 16);
#pragma unroll
        for (int rt = 0; rt < 4; ++rt) {
            const int r = rgrp * 64 + rt * 16 + (l & 15);
            const unsigned swz = (unsigned)((r & 7) << 4);
            const unsigned b0 = (unsigned)((l >> 4) * 32);
            const f32x4 xlo = *(const f32x4*)(XB + cur * 16384 + r * 128 + (b0 ^ swz));
            const f32x4 xhi = *(const f32x4*)(XB + cur * 16384 + r * 128 + ((b0 + 16) ^ swz));
            uint4 u;
            u.x = cvtpk(xlo[0], xlo[1]); u.y = cvtpk(xlo[2], xlo[3]);
            u.z = cvtpk(xhi[0], xhi[1]); u.w = cvtpk(xhi[2], xhi[3]);
            const bf16x8 bX = __builtin_bit_cast(bf16x8, u);
#pragma unroll
            for (int nt = 0; nt < 8; ++nt)
                acc[nt][rt] = __builtin_amdgcn_mfma_f32_16x16x32_bf16(aA[nt], bX, acc[nt][rt], 0, 0, 0);
        }
        __syncthreads();     // drain GLDs; buffers swap
    }

    // ---- epilogue L1: ReLU+BN1 (bias in acc) -> bf16 swizzled Hr[128][1024B] ----
#pragma unroll
    for (int nt = 0; nt < 8; ++nt) {
        const int n0 = (ngrp * 8 + nt) * 16 + ln4;
        const int p = t * 512 + n0;
        const float4 scv = *(const float4*)(P1 + p);
        const float4 shv = *(const float4*)(P1 + 2048 + p);
#pragma unroll
        for (int rt = 0; rt < 4; ++rt) {
            const int r = rgrp * 64 + rt * 16 + (l & 15);
            const f32x4 a = acc[nt][rt];
            const float z0 = fmaf(fmaxf(a[0], 0.f), scv.x, shv.x);
            const float z1 = fmaf(fmaxf(a[1], 0.f), scv.y, shv.y);
            const float z2 = fmaf(fmaxf(a[2], 0.f), scv.z, shv.z);
            const float z3 = fmaf(fmaxf(a[3], 0.f), scv.w, shv.w);
            uint2 pk;
            pk.x = cvtpk(z0, z1); pk.y = cvtpk(z2, z3);
            *(uint2*)(LDS + r * 1024 + (((unsigned)(n0 * 2)) ^ (unsigned)((r & 7) << 4))) = pk;
        }
    }
    __syncthreads();     // Hr complete, cross-wave reads next

    // ---- layer 2: MFMA, outcome o = w, all 128 rows ----
    bf16x8 aW[2][2];     // [kt][ks]
#pragma unroll
    for (int kt = 0; kt < 2; ++kt)
#pragma unroll
        for (int ks = 0; ks < 2; ++ks)
            aW[kt][ks] = *(const bf16x8*)(W2T +
                ((((size_t)t * NO + w) * 2 + kt) * 2 + ks) * 1024 + l * 16);

    f32x4 acc2[2][8];    // [kt][rt2]
#pragma unroll
    for (int kt = 0; kt < 2; ++kt)
#pragma unroll
        for (int rt2 = 0; rt2 < 8; ++rt2) acc2[kt][rt2] = (f32x4){0.f, 0.f, 0.f, 0.f};

#pragma unroll
    for (int rt2 = 0; rt2 < 8; ++rt2) {
        const int r = rt2 * 16 + (l & 15);
        const unsigned swz = (unsigned)((r & 7) << 4);
#pragma unroll
        for (int ks = 0; ks < 2; ++ks) {
            const int n8 = w * 64 + ks * 32 + (l >> 4) * 8;
            const bf16x8 bH = *(const bf16x8*)(LDS + r * 1024 + (((unsigned)(n8 * 2)) ^ swz));
#pragma unroll
            for (int kt = 0; kt < 2; ++kt)
                acc2[kt][rt2] = __builtin_amdgcn_mfma_f32_16x16x32_bf16(aW[kt][ks], bH, acc2[kt][rt2], 0, 0, 0);
        }
    }

    // ---- BN2 + ReLU + layer3 dot (pre-folded), reduce over k-lane-groups ----
    float pr[8];
#pragma unroll
    for (int rt2 = 0; rt2 < 8; ++rt2) pr[rt2] = 0.f;

#pragma unroll
    for (int kt = 0; kt < 2; ++kt) {
        const int q3 = w * 32 + kt * 16 + ln4;
        const int p3 = t * 256 + q3;
        const float4 A3 = *(const float4*)(P2 + p3);
        const float4 C3 = *(const float4*)(P2 + 1024 + p3);
        const float4 bb = *(const float4*)(P2 + 2048 + p3);
#pragma unroll
        for (int rt2 = 0; rt2 < 8; ++rt2) {
            const f32x4 a = acc2[kt][rt2];
            float s = fmaf(fmaxf(a[0] + bb.x, 0.f), A3.x, C3.x);
            s = fmaf(fmaxf(a[1] + bb.y, 0.f), A3.y, s + C3.y);
            s = fmaf(fmaxf(a[2] + bb.z, 0.f), A3.z, s + C3.z);
            s = fmaf(fmaxf(a[3] + bb.w, 0.f), A3.w, s + C3.w);
            pr[rt2] += s;
        }
    }
#pragma unroll
    for (int rt2 = 0; rt2 < 8; ++rt2) {
        float v = pr[rt2];
        v += __shfl_xor(v, 16);
        v += __shfl_xor(v, 32);
        pr[rt2] = v;
    }

    // lane l writes rows (l>>4)*16+(l&15) and ((l>>4)+4)*16+(l&15)
    const float b3v = pb3[w * NT + t];
    const int g = l >> 4;
#pragma unroll
    for (int h = 0; h < 2; ++h) {
        const int rt2 = g + h * 4;
        const int r = rt2 * 16 + (l & 15);
        const int ra = rperm[m0 + r];
        const float v = (g == 0) ? pr[h * 4 + 0] : (g == 1) ? pr[h * 4 + 1]
                       : (g == 2) ? pr[h * 4 + 2] : pr[h * 4 + 3];
        if (ra >= 0) out[(size_t)ra * NO + w] = v + b3v;
    }
}

extern "C" void kernel_launch(void* const* d_in, const int* in_sizes, int n_in,
                              void* d_out, int out_size, void* d_ws, size_t ws_size,
                              hipStream_t stream) {
    const float* X   = (const float*)d_in[0];
    const int* trt   = (const int*)d_in[1];
    const float* W1  = (const float*)d_in[2];
    const float* b1  = (const float*)d_in[3];
    const float* g1  = (const float*)d_in[4];
    const float* be1 = (const float*)d_in[5];
    const float* m1  = (const float*)d_in[6];
    const float* v1  = (const float*)d_in[7];
    const float* W2  = (const float*)d_in[8];
    const float* b2  = (const float*)d_in[9];
    const float* g2  = (const float*)d_in[10];
    const float* be2 = (const float*)d_in[11];
    const float* m2  = (const float*)d_in[12];
    const float* v2  = (const float*)d_in[13];
    const float* W3  = (const float*)d_in[14];
    const float* b3  = (const float*)d_in[15];
    float* out = (float*)d_out;

    const int B = in_sizes[1];
    const int permCap = B + 512;
    int* wsi   = (int*)d_ws;
    int* rperm = wsi + 16;
    char* wsb  = (char*)d_ws;
    size_t off = (64 + (size_t)permCap * 4 + 15) & ~(size_t)15;
    char* W1T = wsb + off;
    char* W2T = W1T + 1048576;
    float* P1 = (float*)(W2T + 131072);
    float* P2 = P1 + 6144;

    hipMemsetAsync(wsi, 0, 64, stream);
    hipMemsetAsync(rperm, 0xFF, (size_t)permCap * 4, stream);

    k_hist_prep<<<556, 256, 0, stream>>>(trt, wsi, B, W1, W2,
                                         b1, g1, be1, m1, v1,
                                         b2, g2, be2, m2, v2, W3,
                                         (unsigned*)W1T, (unsigned*)W2T, P1, P2);
    k_scatter<<<(B + 255) / 256, 256, 0, stream>>>(trt, wsi, rperm, B);

    const int gx = (B + 512) / BM;                  // covers padded buckets
    k_main<<<gx, 512, 0, stream>>>(X, wsi, rperm, W1T, W2T, P1, P2, b3, out);
}

// Round 14
// 60.862 us; speedup vs baseline: 1.2283x; 1.2283x over previous
//
#include <hip/hip_runtime.h>
#include <cstdint>

typedef short bf16x8 __attribute__((ext_vector_type(8)));
typedef float f32x4 __attribute__((ext_vector_type(4)));

#define NO 8
#define NT 4
#define ND 256
#define NH1 64
#define NH2 32
#define BM 32
#define BNEPS 1e-5f

__device__ __forceinline__ unsigned bfpack2(float a, float b) {
    unsigned ua = __float_as_uint(a), ub = __float_as_uint(b);
    ua = (ua + 0x7FFFu + ((ua >> 16) & 1u)) >> 16;
    ub = (ub + 0x7FFFu + ((ub >> 16) & 1u)) >> 16;
    return ua | (ub << 16);
}

__device__ __forceinline__ unsigned cvtpk(float lo, float hi) {
    unsigned r;
    asm("v_cvt_pk_bf16_f32 %0, %1, %2" : "=v"(r) : "v"(lo), "v"(hi));
    return r;
}

// ws layout (bytes):
//   [0,64): int cnt[4] @0, cursor[4] @16  (zeroed by memset)
//   rperm[B+128]: padded slot -> row id (-1 holes; memset 0xFF)
//   W1T (1 MB), W2T (128 KB), P1 (24 KB), P2 (12 KB)

__global__ void k_hist_prep(const int* __restrict__ trt, int* __restrict__ ws, int B,
                            const float* __restrict__ W1, const float* __restrict__ W2,
                            const float* __restrict__ b1, const float* __restrict__ g1,
                            const float* __restrict__ be1, const float* __restrict__ m1,
                            const float* __restrict__ v1,
                            const float* __restrict__ b2, const float* __restrict__ g2,
                            const float* __restrict__ be2, const float* __restrict__ m2,
                            const float* __restrict__ v2, const float* __restrict__ W3,
                            unsigned* __restrict__ W1T4, unsigned* __restrict__ W2T4,
                            float* __restrict__ P1, float* __restrict__ P2) {
    const int bid = blockIdx.x, tid = threadIdx.x;
    if (bid < 256) {                                      // ---- histogram ----
        __shared__ int loc[NT];
        if (tid < NT) loc[tid] = 0;
        __syncthreads();
        const int i = bid * 256 + tid;
        if (i < B) atomicAdd(&loc[trt[i] & 3], 1);
        __syncthreads();
        if (tid < NT) atomicAdd(&ws[tid], loc[tid]);
    } else if (bid < 512) {                               // ---- W1T frags ----
        const int gi = (bid - 256) * 256 + tid;           // 65536
        const int lane = gi & 63, nt = (gi >> 6) & 31, c = (gi >> 11) & 7, t = gi >> 14;
        const int n16 = lane & 15, kg = lane >> 4;
        const int n = nt * 16 + n16, o = n >> 6, h = n & 63;
        const int k0 = c * 32 + kg * 8;
        const float* src = W1 + ((size_t)(o * NT + t) * ND + k0) * NH1 + h;
        float v[8];
#pragma unroll
        for (int j = 0; j < 8; ++j) v[j] = src[(size_t)j * NH1];
        uint4 q;
        q.x = bfpack2(v[0], v[1]); q.y = bfpack2(v[2], v[3]);
        q.z = bfpack2(v[4], v[5]); q.w = bfpack2(v[6], v[7]);
        ((uint4*)W1T4)[gi] = q;
    } else if (bid < 544) {                               // ---- W2T frags ----
        const int gi = (bid - 512) * 256 + tid;           // 8192
        const int m16 = gi & 15, kg = (gi >> 4) & 3, ks = (gi >> 6) & 1,
                  kt = (gi >> 7) & 1, o = (gi >> 8) & 7, t = gi >> 11;
        const int k2 = kt * 16 + m16, hb = ks * 32 + kg * 8;
        const float* src = W2 + ((size_t)(o * NT + t) * NH1 + hb) * NH2 + k2;
        float v[8];
#pragma unroll
        for (int j = 0; j < 8; ++j) v[j] = src[(size_t)j * NH2];
        uint4 q;
        q.x = bfpack2(v[0], v[1]); q.y = bfpack2(v[2], v[3]);
        q.z = bfpack2(v[4], v[5]); q.w = bfpack2(v[6], v[7]);
        ((uint4*)W2T4)[gi] = q;
    } else if (bid < 552) {                               // ---- P1: BN1 fold ----
        const int gi = (bid - 544) * 256 + tid;           // 2048 = 4t x 512n
        const int t = gi >> 9, n = gi & 511;
        const int o = n >> 6, h = n & 63;
        const int idx = (o * NT + t) * NH1 + h;
        const float sc = g1[idx] * rsqrtf(v1[idx] + BNEPS);
        P1[gi] = sc;
        P1[2048 + gi] = be1[idx] - m1[idx] * sc;
        P1[4096 + gi] = b1[idx];
    } else {                                              // ---- P2: BN2+W3 fold ----
        const int gi = (bid - 552) * 256 + tid;           // 1024 = 4t x 256(o,k2)
        const int t = gi >> 8, q = gi & 255;
        const int o = q >> 5, k2 = q & 31;
        const int idx = (o * NT + t) * NH2 + k2;
        const float s = g2[idx] * rsqrtf(v2[idx] + BNEPS);
        const float w3 = W3[idx];
        P2[gi] = s * w3;
        P2[1024 + gi] = (be2[idx] - m2[idx] * s) * w3;
        P2[2048 + gi] = b2[idx];
    }
}

__global__ void k_scatter(const int* __restrict__ trt, int* __restrict__ ws,
                          int* __restrict__ rperm, int B) {
    __shared__ int loc[NT], gb[NT];
    const int tid = threadIdx.x;
    if (tid < NT) loc[tid] = 0;
    __syncthreads();
    const int i = blockIdx.x * blockDim.x + tid;
    int tt = 0, pos = 0;
    if (i < B) { tt = trt[i] & 3; pos = atomicAdd(&loc[tt], 1); }
    __syncthreads();
    if (tid < NT) {
        const int c0 = ws[0], c1 = ws[1], c2 = ws[2];
        const int q0 = (c0 + 31) & ~31, q1 = (c1 + 31) & ~31, q2 = (c2 + 31) & ~31;
        const int eb = tid == 0 ? 0 : tid == 1 ? q0 : tid == 2 ? q0 + q1 : q0 + q1 + q2;
        gb[tid] = eb + atomicAdd(&ws[4 + tid], loc[tid]);
    }
    __syncthreads();
    if (i < B) rperm[gb[tt] + pos] = i;
}

// ---------------- fused 3-layer expert MLP: 32 rows, 8 waves, <=128 regs/wave ----------------
// wave w owns L1 cols [w*64,(w+1)*64) (n-tiles w*4..w*4+3), acc[4][2] = 32 AGPR;
// layer2 outcome o = w reads exactly the cols wave w wrote -> no barrier after epilogue.
__global__ __launch_bounds__(512, 4) void k_main(
    const float* __restrict__ X, const int* __restrict__ ws, const int* __restrict__ rperm,
    const char* __restrict__ W1T, const char* __restrict__ W2T,
    const float* __restrict__ P1, const float* __restrict__ P2,
    const float* __restrict__ pb3, float* __restrict__ out)
{
    const int c0 = ws[0], c1 = ws[1], c2 = ws[2], c3 = ws[3];
    const int q0 = (c0 + 31) & ~31, q1 = (c1 + 31) & ~31, q2 = (c2 + 31) & ~31;
    const int e0 = q0, e1 = q0 + q1, e2 = e1 + q2, e3 = e2 + ((c3 + 31) & ~31);
    const int m0 = blockIdx.x * BM;
    if (m0 >= e3) return;
    const int t = (m0 >= e0) + (m0 >= e1) + (m0 >= e2);

    const int tid = threadIdx.x;
    const int w = tid >> 6;          // 0..7
    const int l = tid & 63;

    // [0,16384): X tile [32 r][512 B] bf16 swizzled; after K-loop: Hr [32 r][1024 B]
    __shared__ __align__(16) char LDS[32768];

    const int rid_o = rperm[m0 + (l & 31)];     // lane l (<32) holds row for slot l

    // ---- stage X: wave w gathers rows w*4..w*4+3, 1 KB coalesced each ----
#pragma unroll
    for (int j = 0; j < 4; ++j) {
        const int r = w * 4 + j;
        const int rr = __shfl(rid_o, r);
        const int rrow = rr < 0 ? 0 : rr;
        const float4 xv = *(const float4*)(X + (size_t)rrow * ND + l * 4);
        uint2 pk;
        pk.x = cvtpk(xv.x, xv.y);
        pk.y = cvtpk(xv.z, xv.w);
        *(uint2*)(LDS + r * 512 + ((l * 8) ^ ((r & 7) << 4))) = pk;
    }

    const char* W1Tw = W1T + (size_t)t * 262144 + (w * 4) * 1024 + l * 16;
    const int ln4 = (l >> 4) * 4;

    // acc init = b1 (bias folded into accumulator)
    f32x4 acc[4][2];
#pragma unroll
    for (int jn = 0; jn < 4; ++jn) {
        const int n0 = (w * 4 + jn) * 16 + ln4;
        const float4 bbv = *(const float4*)(P1 + 4096 + t * 512 + n0);
        acc[jn][0] = (f32x4){bbv.x, bbv.y, bbv.z, bbv.w};
        acc[jn][1] = acc[jn][0];
    }

    __syncthreads();

    // ---- K-loop: W frags from L2 to regs, X frags from LDS; no barriers ----
#pragma unroll
    for (int c = 0; c < 8; ++c) {
        bf16x8 aA[4];
#pragma unroll
        for (int jn = 0; jn < 4; ++jn)
            aA[jn] = *(const bf16x8*)(W1Tw + c * 32768 + jn * 1024);
#pragma unroll
        for (int rt = 0; rt < 2; ++rt) {
            const int r = rt * 16 + (l & 15);
            const bf16x8 bX = *(const bf16x8*)(LDS + r * 512 +
                                               ((c * 64 + (l >> 4) * 16) ^ ((r & 7) << 4)));
#pragma unroll
            for (int jn = 0; jn < 4; ++jn)
                acc[jn][rt] = __builtin_amdgcn_mfma_f32_16x16x32_bf16(aA[jn], bX, acc[jn][rt], 0, 0, 0);
        }
    }
    __syncthreads();     // X reads done; LDS becomes Hr

    // ---- epilogue L1: ReLU+BN1 (bias in acc), bf16 swizzled Hr[32][1024B] ----
#pragma unroll
    for (int jn = 0; jn < 4; ++jn) {
        const int n0 = (w * 4 + jn) * 16 + ln4;
        const int p = t * 512 + n0;
        const float4 scv = *(const float4*)(P1 + p);
        const float4 shv = *(const float4*)(P1 + 2048 + p);
#pragma unroll
        for (int rt = 0; rt < 2; ++rt) {
            const int r = rt * 16 + (l & 15);
            const f32x4 a = acc[jn][rt];
            const float z0 = fmaf(fmaxf(a[0], 0.f), scv.x, shv.x);
            const float z1 = fmaf(fmaxf(a[1], 0.f), scv.y, shv.y);
            const float z2 = fmaf(fmaxf(a[2], 0.f), scv.z, shv.z);
            const float z3 = fmaf(fmaxf(a[3], 0.f), scv.w, shv.w);
            uint2 pk;
            pk.x = cvtpk(z0, z1); pk.y = cvtpk(z2, z3);
            *(uint2*)(LDS + r * 1024 + (((unsigned)(n0 * 2)) ^ (unsigned)((r & 7) << 4))) = pk;
        }
    }
    // wave w wrote cols [w*64,(w+1)*64) = outcome o=w's h-range -> no barrier

    // ---- layer 2: MFMA, outcome o = w ----
    bf16x8 aW[2][2];     // [kt][ks]
#pragma unroll
    for (int kt = 0; kt < 2; ++kt)
#pragma unroll
        for (int ks = 0; ks < 2; ++ks)
            aW[kt][ks] = *(const bf16x8*)(W2T +
                ((((size_t)t * NO + w) * 2 + kt) * 2 + ks) * 1024 + l * 16);

    f32x4 acc2[2][2];    // [kt][rt2]
#pragma unroll
    for (int kt = 0; kt < 2; ++kt)
#pragma unroll
        for (int rt2 = 0; rt2 < 2; ++rt2) acc2[kt][rt2] = (f32x4){0.f, 0.f, 0.f, 0.f};

#pragma unroll
    for (int rt2 = 0; rt2 < 2; ++rt2) {
        const int r = rt2 * 16 + (l & 15);
        const unsigned swz = (unsigned)((r & 7) << 4);
#pragma unroll
        for (int ks = 0; ks < 2; ++ks) {
            const int n8 = w * 64 + ks * 32 + (l >> 4) * 8;
            const bf16x8 bH = *(const bf16x8*)(LDS + r * 1024 + (((unsigned)(n8 * 2)) ^ swz));
#pragma unroll
            for (int kt = 0; kt < 2; ++kt)
                acc2[kt][rt2] = __builtin_amdgcn_mfma_f32_16x16x32_bf16(aW[kt][ks], bH, acc2[kt][rt2], 0, 0, 0);
        }
    }

    // ---- BN2 + ReLU + layer3 dot (pre-folded), reduce over k-lane-groups ----
    float pr[2] = {0.f, 0.f};
#pragma unroll
    for (int kt = 0; kt < 2; ++kt) {
        const int q3 = w * 32 + kt * 16 + ln4;
        const int p3 = t * 256 + q3;
        const float4 A3 = *(const float4*)(P2 + p3);
        const float4 C3 = *(const float4*)(P2 + 1024 + p3);
        const float4 bb = *(const float4*)(P2 + 2048 + p3);
#pragma unroll
        for (int rt2 = 0; rt2 < 2; ++rt2) {
            const f32x4 a = acc2[kt][rt2];
            float s = fmaf(fmaxf(a[0] + bb.x, 0.f), A3.x, C3.x);
            s = fmaf(fmaxf(a[1] + bb.y, 0.f), A3.y, s + C3.y);
            s = fmaf(fmaxf(a[2] + bb.z, 0.f), A3.z, s + C3.z);
            s = fmaf(fmaxf(a[3] + bb.w, 0.f), A3.w, s + C3.w);
            pr[rt2] += s;
        }
    }
#pragma unroll
    for (int rt2 = 0; rt2 < 2; ++rt2) {
        float v = pr[rt2];
        v += __shfl_xor(v, 16);
        v += __shfl_xor(v, 32);
        pr[rt2] = v;
    }

    // lane l (<32) writes row l (rt2 = l>>4), outcome w
    if (l < 32 && rid_o >= 0) {
        const float v = (l >> 4) ? pr[1] : pr[0];
        out[(size_t)rid_o * NO + w] = v + pb3[w * NT + t];
    }
}

extern "C" void kernel_launch(void* const* d_in, const int* in_sizes, int n_in,
                              void* d_out, int out_size, void* d_ws, size_t ws_size,
                              hipStream_t stream) {
    const float* X   = (const float*)d_in[0];
    const int* trt   = (const int*)d_in[1];
    const float* W1  = (const float*)d_in[2];
    const float* b1  = (const float*)d_in[3];
    const float* g1  = (const float*)d_in[4];
    const float* be1 = (const float*)d_in[5];
    const float* m1  = (const float*)d_in[6];
    const float* v1  = (const float*)d_in[7];
    const float* W2  = (const float*)d_in[8];
    const float* b2  = (const float*)d_in[9];
    const float* g2  = (const float*)d_in[10];
    const float* be2 = (const float*)d_in[11];
    const float* m2  = (const float*)d_in[12];
    const float* v2  = (const float*)d_in[13];
    const float* W3  = (const float*)d_in[14];
    const float* b3  = (const float*)d_in[15];
    float* out = (float*)d_out;

    const int B = in_sizes[1];
    const int permCap = B + 128;
    int* wsi   = (int*)d_ws;
    int* rperm = wsi + 16;
    char* wsb  = (char*)d_ws;
    size_t off = (64 + (size_t)permCap * 4 + 15) & ~(size_t)15;
    char* W1T = wsb + off;
    char* W2T = W1T + 1048576;
    float* P1 = (float*)(W2T + 131072);
    float* P2 = P1 + 6144;

    hipMemsetAsync(wsi, 0, 64, stream);
    hipMemsetAsync(rperm, 0xFF, (size_t)permCap * 4, stream);

    k_hist_prep<<<556, 256, 0, stream>>>(trt, wsi, B, W1, W2,
                                         b1, g1, be1, m1, v1,
                                         b2, g2, be2, m2, v2, W3,
                                         (unsigned*)W1T, (unsigned*)W2T, P1, P2);
    k_scatter<<<(B + 255) / 256, 256, 0, stream>>>(trt, wsi, rperm, B);

    const int gx = (B + 128) / 32;                  // covers padded buckets
    k_main<<<gx, 512, 0, stream>>>(X, wsi, rperm, W1T, W2T, P1, P2, b3, out);
}